// Round 3
// baseline (709.205 us; speedup 1.0000x reference)
//
#include <hip/hip_runtime.h>
#include <stdint.h>

// ---------------------------------------------------------------------------
// InvariantPointAttention, N=20000 nodes, E=640000 edges, H=4, S=64, QK=VD=8
//
// Pipeline (all on `stream`):
//   k_zero / k_count / k_scan / k_fill : CSR build (sort edges by dest i),
//              k_fill also emits posmap[e] = CSR position of original edge e
//   k_proj   : tiled per-node projections (32 nodes/block, transposed LDS
//              s-tile for b128 broadcast reads):
//                q_s,k_s (bf16 Nx256), q_v,k_v (rotated+translated bf16 Nx96),
//                v_s (f32 Nx256), v_loc (raw points f32 Nx96, PLANE layout)
//              NOTE: out_scalar == v_s and out_vec == raw v_loc exactly
//              (softmax weights sum to 1; R^-1(R(v)+t-t)=v).
//   k_zproj  : streams z (coalesced), computes b_bias=z@Wb+bb (f32) and
//              pair_z=z@Wdz+bdz (bf16), scatters to CSR positions.
//              bias is written INTO the logits buffer (aliased).
//   k_gather : per CSR edge: gather k_s[i],q_v[i] (cached) + q_s[j],k_v[j],
//              read bias from logits[p], write final logits[p].  Pure
//              gather kernel, loads batched up front for MLP.
//   k_soft   : wave-per-node cooperative softmax (lane=(head,slot)),
//              coalesced logits/pz reads, shuffle reductions -> out_pair
//   k_out    : assemble feats[448] per node + feats @ Wout + bout -> out
// ---------------------------------------------------------------------------

#define C_SQRT83  1.6329931618554518f   // sqrt(8/3)
#define C_SQRT13  0.5773502691896258f   // sqrt(1/3)
#define C_VEC    -0.04811252243246881f  // -0.5*sqrt(1/108)

__device__ __forceinline__ unsigned short f2bf(float f){
  unsigned u = __float_as_uint(f);
  u += 0x7fffu + ((u >> 16) & 1u);          // round-to-nearest-even
  return (unsigned short)(u >> 16);
}
__device__ __forceinline__ unsigned pack2(float a, float b){
  return (unsigned)f2bf(a) | ((unsigned)f2bf(b) << 16);
}
__device__ __forceinline__ float bflo(unsigned u){ return __uint_as_float(u << 16); }
__device__ __forceinline__ float bfhi(unsigned u){ return __uint_as_float(u & 0xffff0000u); }

__device__ __forceinline__ void quat_rot(float w, float ux, float uy, float uz,
                                         float vx, float vy, float vz,
                                         float& ox, float& oy, float& oz){
  float cx = uy*vz - uz*vy;
  float cy = uz*vx - ux*vz;
  float cz = ux*vy - uy*vx;
  float dx = uy*cz - uz*cy;
  float dy = uz*cx - ux*cz;
  float dz = ux*cy - uy*cx;
  ox = vx + 2.f*(w*cx + dx);
  oy = vy + 2.f*(w*cy + dy);
  oz = vz + 2.f*(w*cz + dz);
}

// -------------------------------- CSR build --------------------------------

__global__ __launch_bounds__(256) void k_zero(unsigned* __restrict__ counts, int n){
  int g = blockIdx.x*256 + threadIdx.x;
  if (g < n) counts[g] = 0u;
}

__global__ __launch_bounds__(256) void k_count(const int* __restrict__ ei,
                                               unsigned* __restrict__ counts, int ne){
  int e = blockIdx.x*256 + threadIdx.x;
  if (e >= ne) return;
  atomicAdd(&counts[ei[e]], 1u);
}

__global__ __launch_bounds__(256) void k_scan(const unsigned* __restrict__ counts,
                                              unsigned* __restrict__ row_off,
                                              unsigned* __restrict__ cursor, int n){
  __shared__ unsigned part[256];
  int t = threadIdx.x;
  int chunk = (n + 255) >> 8;
  int s0 = t*chunk, s1 = min(s0 + chunk, n);
  unsigned sum = 0;
  for (int k = s0; k < s1; ++k) sum += counts[k];
  part[t] = sum; __syncthreads();
  for (int off = 1; off < 256; off <<= 1){
    unsigned v = (t >= off) ? part[t-off] : 0u;
    __syncthreads();
    part[t] += v;
    __syncthreads();
  }
  unsigned run = (t == 0) ? 0u : part[t-1];
  for (int k = s0; k < s1; ++k){
    row_off[k] = run; cursor[k] = run; run += counts[k];
  }
  if (t == 255) row_off[n] = part[255];
}

__global__ __launch_bounds__(256) void k_fill(const int* __restrict__ ei,
                                              unsigned* __restrict__ cursor,
                                              unsigned* __restrict__ si,
                                              unsigned* __restrict__ sj,
                                              unsigned* __restrict__ posmap, int ne){
  int e = blockIdx.x*256 + threadIdx.x;
  if (e >= ne) return;
  int i = ei[e];
  unsigned pos = atomicAdd(&cursor[i], 1u);
  si[pos] = (unsigned)i;
  sj[pos] = (unsigned)ei[ne + e];
  posmap[e] = pos;
}

// ------------------------------ node projections ----------------------------
// Block = 32 nodes, 256 threads.  s tile TRANSPOSED in LDS: stT[k][node],
// row stride 40 floats (16B-aligned cols) so per-k node values come from
// broadcast ds_read_b128.
// Scalar matrices (64x256): thread = (cg 0..63 of 4 cols, sl 0..3 of 8 nodes)
// Point matrices (64x96):   thread = (cgp 0..31 [24 active], slp 0..7 of 4 nodes)

#define BN 32

__device__ __forceinline__ void pass256(const float* __restrict__ W,
                                        const float stT[64][40], int cg, int sl,
                                        float acc[8][4]){
  #pragma unroll
  for (int i=0;i<8;i++){ acc[i][0]=0.f; acc[i][1]=0.f; acc[i][2]=0.f; acc[i][3]=0.f; }
  #pragma unroll 4
  for (int k = 0; k < 64; ++k){
    const float4 w  = *(const float4*)(W + (size_t)k*256 + cg*4);
    const float4 n0 = *(const float4*)&stT[k][sl*8];
    const float4 n1 = *(const float4*)&stT[k][sl*8+4];
    acc[0][0]+=n0.x*w.x; acc[0][1]+=n0.x*w.y; acc[0][2]+=n0.x*w.z; acc[0][3]+=n0.x*w.w;
    acc[1][0]+=n0.y*w.x; acc[1][1]+=n0.y*w.y; acc[1][2]+=n0.y*w.z; acc[1][3]+=n0.y*w.w;
    acc[2][0]+=n0.z*w.x; acc[2][1]+=n0.z*w.y; acc[2][2]+=n0.z*w.z; acc[2][3]+=n0.z*w.w;
    acc[3][0]+=n0.w*w.x; acc[3][1]+=n0.w*w.y; acc[3][2]+=n0.w*w.z; acc[3][3]+=n0.w*w.w;
    acc[4][0]+=n1.x*w.x; acc[4][1]+=n1.x*w.y; acc[4][2]+=n1.x*w.z; acc[4][3]+=n1.x*w.w;
    acc[5][0]+=n1.y*w.x; acc[5][1]+=n1.y*w.y; acc[5][2]+=n1.y*w.z; acc[5][3]+=n1.y*w.w;
    acc[6][0]+=n1.z*w.x; acc[6][1]+=n1.z*w.y; acc[6][2]+=n1.z*w.z; acc[6][3]+=n1.z*w.w;
    acc[7][0]+=n1.w*w.x; acc[7][1]+=n1.w*w.y; acc[7][2]+=n1.w*w.z; acc[7][3]+=n1.w*w.w;
  }
}

__device__ __forceinline__ void pass96(const float* __restrict__ W,
                                       const float stT[64][40], int cgp, int slp,
                                       float acc[4][4]){
  #pragma unroll
  for (int i=0;i<4;i++){ acc[i][0]=0.f; acc[i][1]=0.f; acc[i][2]=0.f; acc[i][3]=0.f; }
  if (cgp >= 24) return;
  #pragma unroll 4
  for (int k = 0; k < 64; ++k){
    const float4 w = *(const float4*)(W + (size_t)k*96 + cgp*4);
    const float4 nv = *(const float4*)&stT[k][slp*4];
    acc[0][0]+=nv.x*w.x; acc[0][1]+=nv.x*w.y; acc[0][2]+=nv.x*w.z; acc[0][3]+=nv.x*w.w;
    acc[1][0]+=nv.y*w.x; acc[1][1]+=nv.y*w.y; acc[1][2]+=nv.y*w.z; acc[1][3]+=nv.y*w.w;
    acc[2][0]+=nv.z*w.x; acc[2][1]+=nv.z*w.y; acc[2][2]+=nv.z*w.z; acc[2][3]+=nv.z*w.w;
    acc[3][0]+=nv.w*w.x; acc[3][1]+=nv.w*w.y; acc[3][2]+=nv.w*w.z; acc[3][3]+=nv.w*w.w;
  }
}

__global__ __launch_bounds__(256) void k_proj(
    const float* __restrict__ s, const float* __restrict__ quat, const float* __restrict__ trans,
    const float* __restrict__ Wqs, const float* __restrict__ Wks, const float* __restrict__ Wvs,
    const float* __restrict__ Wqv, const float* __restrict__ Wkv, const float* __restrict__ Wvv,
    unsigned* __restrict__ qs, unsigned* __restrict__ ks, float* __restrict__ vs,
    unsigned* __restrict__ qv, unsigned* __restrict__ kv, float* __restrict__ vv, int n)
{
  __shared__ float stT[64][40];    // transposed s tile (k-major), 16B-aligned cols
  __shared__ float pt[BN][97];     // point staging (x:0..31, y:32..63, z:64..95)
  const int tid = threadIdx.x;
  const int node0 = blockIdx.x * BN;

  // ---- load s tile (BN*64 f32 = 512 float4, 2 per thread), transpose ----
  #pragma unroll
  for (int r = 0; r < 2; ++r){
    const int idx = tid + r*256;          // float4 index
    const int nd = idx >> 4, c4 = idx & 15;
    const int g = node0 + nd;
    float4 v = make_float4(0.f,0.f,0.f,0.f);
    if (g < n) v = *(const float4*)(s + (size_t)g*64 + c4*4);
    stT[c4*4+0][nd]=v.x; stT[c4*4+1][nd]=v.y; stT[c4*4+2][nd]=v.z; stT[c4*4+3][nd]=v.w;
  }
  __syncthreads();

  const int cg = tid & 63, sl = tid >> 6;     // scalar-pass mapping
  const int cgp = tid & 31, slp = tid >> 5;   // point-pass mapping
  float acc[8][4];

  // ---- q_scalar -> bf16 ----
  pass256(Wqs, stT, cg, sl, acc);
  #pragma unroll
  for (int i=0;i<8;i++){
    const int g = node0 + sl*8 + i;
    if (g < n){
      uint2 u; u.x = pack2(acc[i][0],acc[i][1]); u.y = pack2(acc[i][2],acc[i][3]);
      *(uint2*)(qs + (size_t)g*128 + cg*2) = u;
    }
  }
  // ---- k_scalar -> bf16 ----
  pass256(Wks, stT, cg, sl, acc);
  #pragma unroll
  for (int i=0;i<8;i++){
    const int g = node0 + sl*8 + i;
    if (g < n){
      uint2 u; u.x = pack2(acc[i][0],acc[i][1]); u.y = pack2(acc[i][2],acc[i][3]);
      *(uint2*)(ks + (size_t)g*128 + cg*2) = u;
    }
  }
  // ---- v_scalar -> f32 (== out_scalar) ----
  pass256(Wvs, stT, cg, sl, acc);
  #pragma unroll
  for (int i=0;i<8;i++){
    const int g = node0 + sl*8 + i;
    if (g < n){
      float4 f; f.x=acc[i][0]; f.y=acc[i][1]; f.z=acc[i][2]; f.w=acc[i][3];
      *(float4*)(vs + (size_t)g*256 + cg*4) = f;
    }
  }

  // ---- point matrices ----
  float pac[4][4];

  // q_v: rotate + translate -> bf16
  pass96(Wqv, stT, cgp, slp, pac);
  __syncthreads();
  if (cgp < 24){
    #pragma unroll
    for (int i=0;i<4;i++){
      #pragma unroll
      for (int c=0;c<4;c++) pt[slp*4+i][cgp*4+c] = pac[i][c];
    }
  }
  __syncthreads();
  #pragma unroll
  for (int r = 0; r < 2; ++r){
    const int t2 = tid + r*256;
    const int nd = t2 >> 4, pp = t2 & 15;     // point pair 2pp, 2pp+1
    const int g = node0 + nd;
    if (g < n){
      const float4 q4 = *(const float4*)(quat + (size_t)g*4);
      const float tx = trans[(size_t)g*3], ty = trans[(size_t)g*3+1], tz = trans[(size_t)g*3+2];
      float x0,y0,z0,x1,y1,z1;
      quat_rot(q4.x,q4.y,q4.z,q4.w, pt[nd][2*pp],   pt[nd][32+2*pp],   pt[nd][64+2*pp],   x0,y0,z0);
      quat_rot(q4.x,q4.y,q4.z,q4.w, pt[nd][2*pp+1], pt[nd][32+2*pp+1], pt[nd][64+2*pp+1], x1,y1,z1);
      x0+=tx; y0+=ty; z0+=tz; x1+=tx; y1+=ty; z1+=tz;
      unsigned* d = qv + (size_t)g*48 + pp*3;
      d[0] = pack2(x0,y0); d[1] = pack2(z0,x1); d[2] = pack2(y1,z1);
    }
  }

  // k_v: rotate + translate -> bf16
  pass96(Wkv, stT, cgp, slp, pac);
  __syncthreads();
  if (cgp < 24){
    #pragma unroll
    for (int i=0;i<4;i++){
      #pragma unroll
      for (int c=0;c<4;c++) pt[slp*4+i][cgp*4+c] = pac[i][c];
    }
  }
  __syncthreads();
  #pragma unroll
  for (int r = 0; r < 2; ++r){
    const int t2 = tid + r*256;
    const int nd = t2 >> 4, pp = t2 & 15;
    const int g = node0 + nd;
    if (g < n){
      const float4 q4 = *(const float4*)(quat + (size_t)g*4);
      const float tx = trans[(size_t)g*3], ty = trans[(size_t)g*3+1], tz = trans[(size_t)g*3+2];
      float x0,y0,z0,x1,y1,z1;
      quat_rot(q4.x,q4.y,q4.z,q4.w, pt[nd][2*pp],   pt[nd][32+2*pp],   pt[nd][64+2*pp],   x0,y0,z0);
      quat_rot(q4.x,q4.y,q4.z,q4.w, pt[nd][2*pp+1], pt[nd][32+2*pp+1], pt[nd][64+2*pp+1], x1,y1,z1);
      x0+=tx; y0+=ty; z0+=tz; x1+=tx; y1+=ty; z1+=tz;
      unsigned* d = kv + (size_t)g*48 + pp*3;
      d[0] = pack2(x0,y0); d[1] = pack2(z0,x1); d[2] = pack2(y1,z1);
    }
  }

  // v_v: raw (pre-rotation) points == out_vec; store f32 in PLANE layout
  pass96(Wvv, stT, cgp, slp, pac);
  __syncthreads();
  if (cgp < 24){
    #pragma unroll
    for (int i=0;i<4;i++){
      #pragma unroll
      for (int c=0;c<4;c++) pt[slp*4+i][cgp*4+c] = pac[i][c];
    }
  }
  __syncthreads();
  #pragma unroll
  for (int r = 0; r < 12; ++r){
    const int idx = tid + r*256;          // 0..3071
    const int nd = idx / 96, col = idx - nd*96;
    const int g = node0 + nd;
    if (g < n) vv[(size_t)g*96 + col] = pt[nd][col];
  }
}

// --------------------- z-projection (streaming, coalesced) ------------------
// bias (z@Wb+bb) is written into the LOGITS buffer (aliased); k_gather reads
// it from logits[p] and overwrites with the final logit (same thread).

__global__ __launch_bounds__(256) void k_zproj(
    const float* __restrict__ z, const unsigned* __restrict__ posmap,
    const float* __restrict__ Wb,  const float* __restrict__ bb,
    const float* __restrict__ Wdz, const float* __restrict__ bdz,
    float* __restrict__ bias4, unsigned* __restrict__ pz, int ne)
{
  const int e = blockIdx.x*256 + threadIdx.x;
  if (e >= ne) return;
  const unsigned pos = posmap[e];

  float b4[4];  b4[0]=b4[1]=b4[2]=b4[3]=0.f;
  float pacc[16];
  #pragma unroll
  for (int c=0;c<16;c++) pacc[c]=0.f;
  const float* zr = z + (size_t)e*64;
  #pragma unroll
  for (int k4 = 0; k4 < 16; ++k4){
    const float4 zv = *(const float4*)(zr + 4*k4);
    #pragma unroll
    for (int kk = 0; kk < 4; ++kk){
      const int k = 4*k4 + kk;
      const float zk = (kk==0)?zv.x:((kk==1)?zv.y:((kk==2)?zv.z:zv.w));
      const float4 wb = *(const float4*)(Wb + k*4);
      b4[0]+=zk*wb.x; b4[1]+=zk*wb.y; b4[2]+=zk*wb.z; b4[3]+=zk*wb.w;
      const float* wd = Wdz + k*16;
      const float4 w0=*(const float4*)(wd), w1=*(const float4*)(wd+4),
                   w2=*(const float4*)(wd+8), w3=*(const float4*)(wd+12);
      pacc[ 0]+=zk*w0.x; pacc[ 1]+=zk*w0.y; pacc[ 2]+=zk*w0.z; pacc[ 3]+=zk*w0.w;
      pacc[ 4]+=zk*w1.x; pacc[ 5]+=zk*w1.y; pacc[ 6]+=zk*w1.z; pacc[ 7]+=zk*w1.w;
      pacc[ 8]+=zk*w2.x; pacc[ 9]+=zk*w2.y; pacc[10]+=zk*w2.z; pacc[11]+=zk*w2.w;
      pacc[12]+=zk*w3.x; pacc[13]+=zk*w3.y; pacc[14]+=zk*w3.z; pacc[15]+=zk*w3.w;
    }
  }
  {
    float4 b; b.x=b4[0]+bb[0]; b.y=b4[1]+bb[1]; b.z=b4[2]+bb[2]; b.w=b4[3]+bb[3];
    *(float4*)(bias4 + (size_t)pos*4) = b;
  }
  #pragma unroll
  for (int c=0;c<16;c++) pacc[c] += bdz[c];
  { uint4 u0, u1;
    u0.x=pack2(pacc[0],pacc[1]);   u0.y=pack2(pacc[2],pacc[3]);
    u0.z=pack2(pacc[4],pacc[5]);   u0.w=pack2(pacc[6],pacc[7]);
    u1.x=pack2(pacc[8],pacc[9]);   u1.y=pack2(pacc[10],pacc[11]);
    u1.z=pack2(pacc[12],pacc[13]); u1.w=pack2(pacc[14],pacc[15]);
    uint4* d = (uint4*)(pz + (size_t)pos*8);
    d[0]=u0; d[1]=u1; }
}

// ------------------------------- gather kernel ------------------------------

__global__ __launch_bounds__(256) void k_gather(
    const unsigned* __restrict__ si, const unsigned* __restrict__ sj,
    const float* __restrict__ hwts,
    const unsigned* __restrict__ qs, const unsigned* __restrict__ ks,
    const unsigned* __restrict__ qv, const unsigned* __restrict__ kv,
    float* __restrict__ logits, int ne)
{
  const int p = blockIdx.x*256 + threadIdx.x;
  if (p >= ne) return;
  const unsigned i = si[p], j = sj[p];

  const uint4* kr  = (const uint4*)(ks + (size_t)i*128);
  const uint4* qr  = (const uint4*)(qs + (size_t)j*128);
  const uint4* qvr = (const uint4*)(qv + (size_t)i*48);
  const uint4* kvr = (const uint4*)(kv + (size_t)j*48);

  // batch all loads up front for memory-level parallelism
  uint4 ka[8], qa[8], qva[3], kva[3];
  #pragma unroll
  for (int c=0;c<8;c++){ ka[c] = kr[c]; qa[c] = qr[c]; }
  #pragma unroll
  for (int c=0;c<3;c++){ qva[c] = qvr[c]; kva[c] = kvr[c]; }
  const float4 b4 = *(const float4*)(logits + (size_t)p*4);   // bias (aliased)

  // scalar dot per head: k_s[i] . q_s[j]
  float sdot[4];
  #pragma unroll
  for (int h = 0; h < 4; ++h){
    float acc = 0.f;
    #pragma unroll
    for (int c = 0; c < 2; ++c){
      const uint4 a = ka[h*2+c];
      const uint4 b = qa[h*2+c];
      acc += bflo(a.x)*bflo(b.x) + bfhi(a.x)*bfhi(b.x);
      acc += bflo(a.y)*bflo(b.y) + bfhi(a.y)*bfhi(b.y);
      acc += bflo(a.z)*bflo(b.z) + bfhi(a.z)*bfhi(b.z);
      acc += bflo(a.w)*bflo(b.w) + bfhi(a.w)*bfhi(b.w);
    }
    sdot[h] = acc;
  }
  // NOTE: head h spans uint4 indices h*2, h*2+1 (8 dwords = 16 bf16 = ... )
  // careful: 64 dims per head = 32 dwords per head? No: 256 cols / 4 heads =
  // 64 cols = 32 dwords = 2 uint4?  32 dwords = 8 uint4 total/4 heads = 2 each.
  // (8 uint4 total = 32 dwords = 64 bf16... that's 64 cols TOTAL.)
  // -> WRONG if left as-is; fixed below by full-width accumulate.

  // vector attention: sum_p |q_v[i]-k_v[j]|^2 per head (24 dwords = 48 bf16)
  float vsum[4];
  {
    float acch[4];
    #pragma unroll
    for (int h=0;h<4;h++) acch[h]=0.f;
    #pragma unroll
    for (int c = 0; c < 3; ++c){
      const uint4 a = qva[c], b = kva[c];
      const int base = c*8;                 // dword index = c*4.. each has 2 bf16
      float d;
      d = bflo(a.x)-bflo(b.x); acch[(base+0)/6] += d*d;
      d = bfhi(a.x)-bfhi(b.x); acch[(base+1)/6] += d*d;
      d = bflo(a.y)-bflo(b.y); acch[(base+2)/6] += d*d;
      d = bfhi(a.y)-bfhi(b.y); acch[(base+3)/6] += d*d;
      d = bflo(a.z)-bflo(b.z); acch[(base+4)/6] += d*d;
      d = bfhi(a.z)-bfhi(b.z); acch[(base+5)/6] += d*d;
      d = bflo(a.w)-bflo(b.w); acch[(base+6)/6] += d*d;
      d = bfhi(a.w)-bfhi(b.w); acch[(base+7)/6] += d*d;
    }
    #pragma unroll
    for (int h=0;h<4;h++) vsum[h]=acch[h];
  }

  float4 lg;
  {
    float l[4];
    #pragma unroll
    for (int h = 0; h < 4; ++h){
      const float hw = log1pf(__expf(hwts[h]));   // softplus
      l[h] = C_SQRT83*sdot[h] + C_SQRT13*b4.x + C_VEC*hw*vsum[h];
    }
    lg.x=l[0]; lg.y=l[1]; lg.z=l[2]; lg.w=l[3];
  }
  *(float4*)(logits + (size_t)p*4) = lg;
}

// The scalar tables are 256 bf16 per node = 128 dwords = 32 uint4; per head
// that's 8 uint4.  The compact version above under-counted; use this full
// kernel instead (the one actually launched).
__global__ __launch_bounds__(256) void k_gather_full(
    const unsigned* __restrict__ si, const unsigned* __restrict__ sj,
    const float* __restrict__ hwts,
    const unsigned* __restrict__ qs, const unsigned* __restrict__ ks,
    const unsigned* __restrict__ qv, const unsigned* __restrict__ kv,
    float* __restrict__ logits, int ne)
{
  const int p = blockIdx.x*256 + threadIdx.x;
  if (p >= ne) return;
  const unsigned i = si[p], j = sj[p];

  const uint4* kr  = (const uint4*)(ks + (size_t)i*128);
  const uint4* qr  = (const uint4*)(qs + (size_t)j*128);
  const uint4* qvr = (const uint4*)(qv + (size_t)i*48);
  const uint4* kvr = (const uint4*)(kv + (size_t)j*48);

  uint4 qva[3], kva[3];
  #pragma unroll
  for (int c=0;c<3;c++){ qva[c] = qvr[c]; kva[c] = kvr[c]; }
  const float4 b4 = *(const float4*)(logits + (size_t)p*4);   // bias (aliased)

  // scalar dot per head: 8 uint4 per head; batch loads per head-pair to
  // keep VGPR moderate while retaining MLP (16 loads in flight).
  float sdot[4];
  #pragma unroll
  for (int hp = 0; hp < 2; ++hp){
    uint4 a0[8], b0[8];
    #pragma unroll
    for (int c=0;c<8;c++){ a0[c]=kr[hp*16+c]; b0[c]=qr[hp*16+c]; }
    uint4 a1[8], b1[8];
    #pragma unroll
    for (int c=0;c<8;c++){ a1[c]=kr[hp*16+8+c]; b1[c]=qr[hp*16+8+c]; }
    float acc0 = 0.f, acc1 = 0.f;
    #pragma unroll
    for (int c=0;c<8;c++){
      const uint4 a = a0[c], b = b0[c];
      acc0 += bflo(a.x)*bflo(b.x) + bfhi(a.x)*bfhi(b.x);
      acc0 += bflo(a.y)*bflo(b.y) + bfhi(a.y)*bfhi(b.y);
      acc0 += bflo(a.z)*bflo(b.z) + bfhi(a.z)*bfhi(b.z);
      acc0 += bflo(a.w)*bflo(b.w) + bfhi(a.w)*bfhi(b.w);
    }
    #pragma unroll
    for (int c=0;c<8;c++){
      const uint4 a = a1[c], b = b1[c];
      acc1 += bflo(a.x)*bflo(b.x) + bfhi(a.x)*bfhi(b.x);
      acc1 += bflo(a.y)*bflo(b.y) + bfhi(a.y)*bfhi(b.y);
      acc1 += bflo(a.z)*bflo(b.z) + bfhi(a.z)*bfhi(b.z);
      acc1 += bflo(a.w)*bflo(b.w) + bfhi(a.w)*bfhi(b.w);
    }
    sdot[hp*2]   = acc0;
    sdot[hp*2+1] = acc1;
  }

  // vector attention: per head 6 dwords (12 bf16 = 8 pts x 3 wait: 24 bf16/hd)
  // qv row = 96 bf16 = 48 dwords = 12 uint4?  No: 96 bf16 = 48 dwords... row
  // is 48 unsigneds = 12 uint4.  Head h occupies dwords h*12..h*12+11.
  const uint4* qvr4 = (const uint4*)(qv + (size_t)i*48);
  const uint4* kvr4 = (const uint4*)(kv + (size_t)j*48);
  float vsum[4];
  #pragma unroll
  for (int h = 0; h < 4; ++h){
    const uint4 a0 = qvr4[h*3], a1 = qvr4[h*3+1], a2 = qvr4[h*3+2];
    const uint4 b0 = kvr4[h*3], b1 = kvr4[h*3+1], b2 = kvr4[h*3+2];
    float acc = 0.f, d;
    d=bflo(a0.x)-bflo(b0.x); acc+=d*d; d=bfhi(a0.x)-bfhi(b0.x); acc+=d*d;
    d=bflo(a0.y)-bflo(b0.y); acc+=d*d; d=bfhi(a0.y)-bfhi(b0.y); acc+=d*d;
    d=bflo(a0.z)-bflo(b0.z); acc+=d*d; d=bfhi(a0.z)-bfhi(b0.z); acc+=d*d;
    d=bflo(a0.w)-bflo(b0.w); acc+=d*d; d=bfhi(a0.w)-bfhi(b0.w); acc+=d*d;
    d=bflo(a1.x)-bflo(b1.x); acc+=d*d; d=bfhi(a1.x)-bfhi(b1.x); acc+=d*d;
    d=bflo(a1.y)-bflo(b1.y); acc+=d*d; d=bfhi(a1.y)-bfhi(b1.y); acc+=d*d;
    d=bflo(a1.z)-bflo(b1.z); acc+=d*d; d=bfhi(a1.z)-bfhi(b1.z); acc+=d*d;
    d=bflo(a1.w)-bflo(b1.w); acc+=d*d; d=bfhi(a1.w)-bfhi(b1.w); acc+=d*d;
    d=bflo(a2.x)-bflo(b2.x); acc+=d*d; d=bfhi(a2.x)-bfhi(b2.x); acc+=d*d;
    d=bflo(a2.y)-bflo(b2.y); acc+=d*d; d=bfhi(a2.y)-bfhi(b2.y); acc+=d*d;
    d=bflo(a2.z)-bflo(b2.z); acc+=d*d; d=bfhi(a2.z)-bfhi(b2.z); acc+=d*d;
    d=bflo(a2.w)-bflo(b2.w); acc+=d*d; d=bfhi(a2.w)-bfhi(b2.w); acc+=d*d;
    vsum[h] = acc;
  }
  (void)qva; (void)kva;

  float4 lg;
  {
    float bias[4] = {b4.x, b4.y, b4.z, b4.w};
    float l[4];
    #pragma unroll
    for (int h = 0; h < 4; ++h){
      const float hw = log1pf(__expf(hwts[h]));   // softplus
      l[h] = C_SQRT83*sdot[h] + C_SQRT13*bias[h] + C_VEC*hw*vsum[h];
    }
    lg.x=l[0]; lg.y=l[1]; lg.z=l[2]; lg.w=l[3];
  }
  *(float4*)(logits + (size_t)p*4) = lg;
}

// ----------------------- wave-per-node softmax + pair -----------------------
// lane = h*16 + sub : head h (0..3), edge slot sub (0..15).
// logits reads are 64 consecutive dwords per iteration; pz reads contiguous.

__global__ __launch_bounds__(256) void k_soft(
    const float* __restrict__ logits, const unsigned* __restrict__ pz,
    const unsigned* __restrict__ row_off, float* __restrict__ out_pair, int n)
{
  const int node = blockIdx.x*4 + (threadIdx.x >> 6);
  if (node >= n) return;
  const int lane = threadIdx.x & 63;
  const int h = lane >> 4, sub = lane & 15;
  const int beg = (int)row_off[node], end = (int)row_off[node+1];

  float m = -3.4e38f;
  for (int p = beg + sub; p < end; p += 16)
    m = fmaxf(m, logits[(size_t)p*4 + h]);
  #pragma unroll
  for (int msk = 1; msk < 16; msk <<= 1)
    m = fmaxf(m, __shfl_xor(m, msk));

  float ssum = 0.f;
  float acc[16];
  #pragma unroll
  for (int c=0;c<16;c++) acc[c]=0.f;

  for (int p = beg + sub; p < end; p += 16){
    const float w = __expf(logits[(size_t)p*4 + h] - m);
    ssum += w;
    const uint4* pr = (const uint4*)(pz + (size_t)p*8);
    const uint4 a = pr[0], b = pr[1];
    acc[ 0]+=w*bflo(a.x); acc[ 1]+=w*bfhi(a.x);
    acc[ 2]+=w*bflo(a.y); acc[ 3]+=w*bfhi(a.y);
    acc[ 4]+=w*bflo(a.z); acc[ 5]+=w*bfhi(a.z);
    acc[ 6]+=w*bflo(a.w); acc[ 7]+=w*bfhi(a.w);
    acc[ 8]+=w*bflo(b.x); acc[ 9]+=w*bfhi(b.x);
    acc[10]+=w*bflo(b.y); acc[11]+=w*bfhi(b.y);
    acc[12]+=w*bflo(b.z); acc[13]+=w*bfhi(b.z);
    acc[14]+=w*bflo(b.w); acc[15]+=w*bfhi(b.w);
  }
  #pragma unroll
  for (int msk = 1; msk < 16; msk <<= 1){
    ssum += __shfl_xor(ssum, msk);
    #pragma unroll
    for (int c=0;c<16;c++) acc[c] += __shfl_xor(acc[c], msk);
  }
  const float inv = (end > beg) ? (1.f/ssum) : 0.f;
  float r = 0.f;
  #pragma unroll
  for (int c=0;c<16;c++) if (c == sub) r = acc[c];
  out_pair[(size_t)node*64 + lane] = r * inv;
}

// --------------------- feats assembly + output GEMM ------------------------

__global__ __launch_bounds__(256) void k_out(
    const float* __restrict__ vs, const float* __restrict__ vv,
    const float* __restrict__ out_pair, const unsigned* __restrict__ row_off,
    const float* __restrict__ quat, const float* __restrict__ trans,
    const float* __restrict__ Wout, const float* __restrict__ bout,
    float* __restrict__ out, int n)
{
  __shared__ float feats[32][448];
  __shared__ int degs[32];
  const int tid = threadIdx.x;
  const int node0 = blockIdx.x*32;

  if (tid < 32){
    const int g = node0 + tid;
    degs[tid] = (g < n) ? (int)(row_off[g+1] - row_off[g]) : 1;
  }
  __syncthreads();

  // out_scalar == v_scalar (softmax weights sum to 1), 0 for empty segments
  for (int x = tid; x < 32*256; x += 256){
    const int nd = x >> 8, c = x & 255;
    const int g = node0 + nd;
    feats[nd][c] = (g < n && degs[nd] > 0) ? vs[(size_t)g*256 + c] : 0.f;
  }
  // out_pair
  for (int x = tid; x < 32*64; x += 256){
    const int nd = x >> 6, c = x & 63;
    const int g = node0 + nd;
    feats[nd][384 + c] = (g < n) ? out_pair[(size_t)g*64 + c] : 0.f;
  }
  // out_vec == raw local points (vv is PLANE layout: x 0..31, y 32..63, z 64..95)
  for (int x = tid; x < 32*32; x += 256){
    const int nd = x >> 5, pt = x & 31;
    const int g = node0 + nd;
    float X=0.f, Y=0.f, Z=0.f;
    if (g < n){
      if (degs[nd] > 0){
        X = vv[(size_t)g*96 + pt];
        Y = vv[(size_t)g*96 + 32 + pt];
        Z = vv[(size_t)g*96 + 64 + pt];
      } else {
        const float4 q4 = *(const float4*)(quat + (size_t)g*4);
        const float tx = trans[(size_t)g*3], ty = trans[(size_t)g*3+1], tz = trans[(size_t)g*3+2];
        quat_rot(q4.x, -q4.y, -q4.z, -q4.w, -tx, -ty, -tz, X, Y, Z);
      }
    }
    feats[nd][256 + pt] = X;
    feats[nd][288 + pt] = Y;
    feats[nd][320 + pt] = Z;
    feats[nd][352 + pt] = sqrtf(X*X + Y*Y + Z*Z + 1e-8f);
  }
  __syncthreads();

  // GEMM: wave computes 8 nodes x 64 cols; k unrolled x4 with b128 broadcast
  // reads of feats rows; Wout streamed coalesced.
  const int lane = tid & 63;
  const int wave = tid >> 6;
  float acc[8];
  #pragma unroll
  for (int q8=0;q8<8;q8++) acc[q8]=0.f;

  for (int k0 = 0; k0 < 448; k0 += 4){
    const float w0 = Wout[(size_t)(k0+0)*64 + lane];
    const float w1 = Wout[(size_t)(k0+1)*64 + lane];
    const float w2 = Wout[(size_t)(k0+2)*64 + lane];
    const float w3 = Wout[(size_t)(k0+3)*64 + lane];
    #pragma unroll
    for (int q8 = 0; q8 < 8; ++q8){
      const float4 f = *(const float4*)&feats[wave*8 + q8][k0];
      acc[q8] += f.x*w0 + f.y*w1 + f.z*w2 + f.w*w3;
    }
  }
  const float bo = bout[lane];
  #pragma unroll
  for (int q8 = 0; q8 < 8; ++q8){
    const int g = node0 + wave*8 + q8;
    if (g < n) out[(size_t)g*64 + lane] = acc[q8] + bo;
  }
}

// --------------------------------- launch ----------------------------------

extern "C" void kernel_launch(void* const* d_in, const int* in_sizes, int n_in,
                              void* d_out, int out_size, void* d_ws, size_t ws_size,
                              hipStream_t stream) {
  const float* s     = (const float*)d_in[0];
  const float* z     = (const float*)d_in[1];
  const int*   ei    = (const int*)  d_in[2];
  const float* quat  = (const float*)d_in[3];
  const float* trans = (const float*)d_in[4];
  const float* Wqs   = (const float*)d_in[5];
  const float* Wks   = (const float*)d_in[6];
  const float* Wvs   = (const float*)d_in[7];
  const float* Wqv   = (const float*)d_in[8];
  const float* Wkv   = (const float*)d_in[9];
  const float* Wvv   = (const float*)d_in[10];
  const float* Wb    = (const float*)d_in[11];
  const float* bb    = (const float*)d_in[12];
  const float* Wdz   = (const float*)d_in[13];
  const float* bdz   = (const float*)d_in[14];
  const float* hwts  = (const float*)d_in[15];
  const float* Wout  = (const float*)d_in[16];
  const float* bout  = (const float*)d_in[17];
  float* out = (float*)d_out;

  const int n  = in_sizes[0] / 64;   // 20000
  const int ne = in_sizes[1] / 64;   // 640000

  size_t off = 0;
  char* base = (char*)d_ws;
  auto take = [&](size_t bytes)->char* {
    char* p = base + off;
    off += (bytes + 255) & ~(size_t)255;
    return p;
  };
  unsigned* qs     = (unsigned*)take((size_t)n*512);    // bf16 N x 256
  unsigned* ks     = (unsigned*)take((size_t)n*512);    // bf16 N x 256
  unsigned* qvt    = (unsigned*)take((size_t)n*192);    // bf16 N x 96 (rot + t)
  unsigned* kvt    = (unsigned*)take((size_t)n*192);    // bf16 N x 96 (rot + t)
  float*    vs     = (float*)   take((size_t)n*1024);   // f32  N x 256
  float*    vv     = (float*)   take((size_t)n*384);    // f32  N x 96 (raw, planes)
  float*    logits = (float*)   take((size_t)ne*16);    // f32  E x 4 (CSR; bias then logits)
  unsigned* pz     = (unsigned*)take((size_t)ne*32);    // bf16 E x 16 (CSR order)
  unsigned* counts = (unsigned*)take((size_t)n*4);
  unsigned* roff   = (unsigned*)take((size_t)(n+1)*4);
  unsigned* cur    = (unsigned*)take((size_t)n*4);
  unsigned* si     = (unsigned*)take((size_t)ne*4);
  unsigned* sj     = (unsigned*)take((size_t)ne*4);
  unsigned* posmap = (unsigned*)take((size_t)ne*4);
  float*    opair  = (float*)   take((size_t)n*256);    // f32  N x 64
  (void)ws_size; (void)n_in; (void)out_size;

  const int gbE = (ne + 255) / 256;
  const int gbN = (n  + 255) / 256;

  k_zero <<<gbN, 256, 0, stream>>>(counts, n);
  k_count<<<gbE, 256, 0, stream>>>(ei, counts, ne);
  k_scan <<<1,   256, 0, stream>>>(counts, roff, cur, n);
  k_fill <<<gbE, 256, 0, stream>>>(ei, cur, si, sj, posmap, ne);
  k_proj <<<(n + BN - 1)/BN, 256, 0, stream>>>(s, quat, trans, Wqs, Wks, Wvs, Wqv, Wkv, Wvv,
                                               qs, ks, vs, qvt, kvt, vv, n);
  k_zproj<<<gbE, 256, 0, stream>>>(z, posmap, Wb, bb, Wdz, bdz, logits, pz, ne);
  k_gather_full<<<gbE, 256, 0, stream>>>(si, sj, hwts, qs, ks, qvt, kvt, logits, ne);
  k_soft <<<(n + 3)/4, 256, 0, stream>>>(logits, pz, roff, opair, n);
  k_out  <<<(n + 31)/32, 256, 0, stream>>>(vs, vv, opair, roff, quat, trans,
                                           Wout, bout, out, n);
}